// Round 1
// baseline (452.827 us; speedup 1.0000x reference)
//
#include <hip/hip_runtime.h>

// Cumulative max along H for x of shape [B=32, C=1, H=1024, W=2048], fp32.
// out[b, 0, h, w] = max_{h' <= h} x[b, 0, h', w]
//
// Parallelism: one thread per PAIR of adjacent columns (float2 loads/stores,
// 8 B/lane). 65,536 columns -> 32,768 threads -> 512 blocks x 64 threads
// (1 wave/block, ~2 blocks/CU across 256 CUs). Each thread walks H
// sequentially with a running max; unroll 16 keeps ~8 KB of loads in flight
// per wave to cover ~900-cycle HBM latency.

#define B 32
#define H 1024
#define W 2048

__global__ __launch_bounds__(64) void cummax_h_kernel(
    const float* __restrict__ x, float* __restrict__ out) {
  const int p  = blockIdx.x * 64 + threadIdx.x;  // pair index: 0 .. B*W/2-1
  const int b  = p >> 10;                        // W/2 = 1024 pairs per batch
  const int wp = p & 1023;

  const size_t base = ((size_t)b << 20) + (size_t)wp;  // in float2 units; H*W/2 = 1<<20
  const float2* __restrict__ px = reinterpret_cast<const float2*>(x) + base;
  float2* __restrict__ po       = reinterpret_cast<float2*>(out) + base;

  float2 m;
  m.x = -__builtin_inff();
  m.y = -__builtin_inff();

#pragma unroll 16
  for (int h = 0; h < H; ++h) {
    float2 v = px[(size_t)h * (W / 2)];
    m.x = fmaxf(m.x, v.x);
    m.y = fmaxf(m.y, v.y);
    po[(size_t)h * (W / 2)] = m;
  }
}

extern "C" void kernel_launch(void* const* d_in, const int* in_sizes, int n_in,
                              void* d_out, int out_size, void* d_ws, size_t ws_size,
                              hipStream_t stream) {
  const float* x = (const float*)d_in[0];
  float* out = (float*)d_out;

  const int n_pairs = B * W / 2;         // 32768
  const int block = 64;
  const int grid = n_pairs / block;      // 512
  cummax_h_kernel<<<grid, block, 0, stream>>>(x, out);
}

// Round 3
// 427.257 us; speedup vs baseline: 1.0598x; 1.0598x over previous
//
#include <hip/hip_runtime.h>

// Cumulative max along H for x of shape [B=32, C=1, H=1024, W=2048], fp32.
// out[b, 0, h, w] = max_{h' <= h} x[b, 0, h', w]
//
// R2 design (resubmitted after broker timeout):
//  - One thread per column: 65,536 threads = 256 blocks x 256 threads
//    -> 4 waves/CU (one per SIMD) across all 256 CUs.
//  - Register double-buffer of CH=16 rows: loads of chunk k+1 are issued
//    before the compute+store of chunk k, so each wave keeps 16 loads
//    (16 x 256 B/wave) in flight. 4 waves/CU -> ~16 KB outstanding loads/CU,
//    comfortably above the ~4.6 KB needed to sustain the load half of
//    6.3 TB/s at ~900-cycle HBM latency.
//  - bufA/bufB are separate named arrays with static indices only (runtime
//    indexing would spill to scratch).

#define B 32
#define H 1024
#define W 2048
#define CH 16            // rows per chunk
#define NCHUNK (H / CH)  // 64 (even)

__global__ __launch_bounds__(256) void cummax_h_kernel(
    const float* __restrict__ x, float* __restrict__ out) {
  const int col = blockIdx.x * 256 + threadIdx.x;  // 0 .. B*W-1
  const int b = col >> 11;                         // W = 2048 columns per batch
  const int w = col & (W - 1);

  const size_t base = (size_t)b * (H * W) + (size_t)w;
  const float* __restrict__ px = x + base;
  float* __restrict__ po = out + base;

  float bufA[CH], bufB[CH];
  float m = -__builtin_inff();

  // Prologue: load chunk 0 into A.
#pragma unroll
  for (int i = 0; i < CH; ++i) bufA[i] = px[(size_t)i * W];
  px += (size_t)CH * W;

  // Main loop: 31 iterations, each consumes chunks c (A) and c+1 (B) while
  // prefetching c+1 and c+2.
  for (int c = 0; c < NCHUNK - 2; c += 2) {
    // prefetch chunk c+1 -> B
#pragma unroll
    for (int i = 0; i < CH; ++i) bufB[i] = px[(size_t)i * W];
    px += (size_t)CH * W;

    // consume chunk c from A
#pragma unroll
    for (int i = 0; i < CH; ++i) {
      m = fmaxf(m, bufA[i]);
      po[(size_t)i * W] = m;
    }
    po += (size_t)CH * W;

    // prefetch chunk c+2 -> A
#pragma unroll
    for (int i = 0; i < CH; ++i) bufA[i] = px[(size_t)i * W];
    px += (size_t)CH * W;

    // consume chunk c+1 from B
#pragma unroll
    for (int i = 0; i < CH; ++i) {
      m = fmaxf(m, bufB[i]);
      po[(size_t)i * W] = m;
    }
    po += (size_t)CH * W;
  }

  // Epilogue: chunks NCHUNK-2 (in A) and NCHUNK-1.
#pragma unroll
  for (int i = 0; i < CH; ++i) bufB[i] = px[(size_t)i * W];
#pragma unroll
  for (int i = 0; i < CH; ++i) {
    m = fmaxf(m, bufA[i]);
    po[(size_t)i * W] = m;
  }
  po += (size_t)CH * W;
#pragma unroll
  for (int i = 0; i < CH; ++i) {
    m = fmaxf(m, bufB[i]);
    po[(size_t)i * W] = m;
  }
}

extern "C" void kernel_launch(void* const* d_in, const int* in_sizes, int n_in,
                              void* d_out, int out_size, void* d_ws, size_t ws_size,
                              hipStream_t stream) {
  const float* x = (const float*)d_in[0];
  float* out = (float*)d_out;

  const int n_cols = B * W;            // 65536
  const int block = 256;
  const int grid = n_cols / block;     // 256 blocks -> 1 per CU, 4 waves/CU
  cummax_h_kernel<<<grid, block, 0, stream>>>(x, out);
}